// Round 1
// baseline (1063.824 us; speedup 1.0000x reference)
//
#include <hip/hip_runtime.h>
#include <math.h>

#define BM 128
#define BN 128
#define BK 16

#define DMODEL 512
#define DINNER 1024
#define DSTATE 16
#define SEQLEN 2048
#define NTOK   4096            // BATCH * LENGTH
#define CHUNK  64
#define NCHUNK (SEQLEN / CHUNK)  // 32

__device__ __forceinline__ float silu_f(float x) {
    return x / (1.0f + expf(-x));
}

// MODE 0: plain store C = A@B
// MODE 1: conv  — A is x_z (inside x_proj, lda=2048); flat K index r -> (k=r>>10, i=r&1023),
//                 reads x_z[token + k - 1, i] with batch-aware zero pad; epilogue silu(acc+bias[n])
// MODE 2: delta — epilogue w = softplus(acc + bias[n]) * xc[m,n] * 0.95^(l+1)
template<int MODE>
__global__ __launch_bounds__(256)
void gemm_k(const float* __restrict__ A, int lda,
            const float* __restrict__ B, int ldb,
            float* __restrict__ C, int ldc,
            int M, int N, int K,
            const float* __restrict__ bias,
            const float* __restrict__ xc)
{
    __shared__ float As[BK][BM + 4];
    __shared__ float Bs[BK][BN + 4];
    const int bm = blockIdx.y * BM;
    const int bn = blockIdx.x * BN;
    const int tid = threadIdx.x;
    const int tr = tid >> 4;   // 0..15
    const int tc = tid & 15;   // 0..15

    float acc[8][8];
#pragma unroll
    for (int i = 0; i < 8; ++i)
#pragma unroll
        for (int j = 0; j < 8; ++j) acc[i][j] = 0.0f;

    for (int k0 = 0; k0 < K; k0 += BK) {
        // ---- load A tile (128 rows x 16 k), transpose into As[k][m]
#pragma unroll
        for (int q = 0; q < 2; ++q) {
            int lin = tid + q * 256;        // 0..511
            int row = lin >> 2;             // 0..127
            int kq  = (lin & 3) << 2;       // 0,4,8,12
            int m   = bm + row;
            float4 v;
            if (MODE == 1) {
                int r   = k0 + kq;
                int kid = r >> 10;
                int i   = r & 1023;
                int l2  = (m & (SEQLEN - 1)) + kid - 1;
                if ((unsigned)l2 < (unsigned)SEQLEN) {
                    v = *reinterpret_cast<const float4*>(A + (size_t)(m + kid - 1) * lda + i);
                } else {
                    v = make_float4(0.f, 0.f, 0.f, 0.f);
                }
            } else {
                v = *reinterpret_cast<const float4*>(A + (size_t)m * lda + k0 + kq);
            }
            As[kq + 0][row] = v.x;
            As[kq + 1][row] = v.y;
            As[kq + 2][row] = v.z;
            As[kq + 3][row] = v.w;
        }
        // ---- load B tile (16 k x 128 cols)
#pragma unroll
        for (int q = 0; q < 2; ++q) {
            int lin = tid + q * 256;
            int kr  = lin >> 5;             // 0..15
            int c4  = (lin & 31) << 2;      // 0..124
            float4 v = *reinterpret_cast<const float4*>(B + (size_t)(k0 + kr) * ldb + bn + c4);
            *reinterpret_cast<float4*>(&Bs[kr][c4]) = v;
        }
        __syncthreads();
#pragma unroll
        for (int kk = 0; kk < BK; ++kk) {
            float4 a0 = *reinterpret_cast<const float4*>(&As[kk][tr * 8]);
            float4 a1 = *reinterpret_cast<const float4*>(&As[kk][tr * 8 + 4]);
            float4 b0 = *reinterpret_cast<const float4*>(&Bs[kk][tc * 8]);
            float4 b1 = *reinterpret_cast<const float4*>(&Bs[kk][tc * 8 + 4]);
            float a[8] = {a0.x, a0.y, a0.z, a0.w, a1.x, a1.y, a1.z, a1.w};
            float b[8] = {b0.x, b0.y, b0.z, b0.w, b1.x, b1.y, b1.z, b1.w};
#pragma unroll
            for (int i = 0; i < 8; ++i)
#pragma unroll
                for (int j = 0; j < 8; ++j)
                    acc[i][j] = fmaf(a[i], b[j], acc[i][j]);
        }
        __syncthreads();
    }

    const float LOG095 = -0.051293294f;
#pragma unroll
    for (int i = 0; i < 8; ++i) {
        int m = bm + tr * 8 + i;
        float dec = 0.0f;
        if (MODE == 2) {
            int l = m & (SEQLEN - 1);
            dec = expf((float)(l + 1) * LOG095);
        }
#pragma unroll
        for (int j = 0; j < 8; ++j) {
            int n = bn + tc * 8 + j;
            float v = acc[i][j];
            if (MODE == 1) {
                v = silu_f(v + bias[n]);
            } else if (MODE == 2) {
                float d  = v + bias[n];
                float sp = fmaxf(d, 0.f) + log1pf(expf(-fabsf(d)));
                v = sp * xc[(size_t)m * DINNER + n] * dec;
            }
            C[(size_t)m * ldc + n] = v;
        }
    }
}

// Bm = xc@wB + bB ; Cm = xc@wC + bC   (one token per block)
__global__ __launch_bounds__(256)
void bc_k(const float* __restrict__ xc,
          const float* __restrict__ wB, const float* __restrict__ bB,
          const float* __restrict__ wC, const float* __restrict__ bC,
          float* __restrict__ Bm, float* __restrict__ Cm)
{
    __shared__ float xr[DINNER];
    __shared__ float part[8][32];
    int t = blockIdx.x;
    int tid = threadIdx.x;
#pragma unroll
    for (int q = 0; q < 4; ++q) {
        int i = tid + q * 256;
        xr[i] = xc[(size_t)t * DINNER + i];
    }
    __syncthreads();
    int s = tid & 31;       // 0..15 -> B, 16..31 -> C
    int p = tid >> 5;       // 0..7
    const float* W = (s < 16) ? wB : wC;
    int col = s & 15;
    float acc = 0.f;
    for (int k = p * 128; k < p * 128 + 128; ++k)
        acc += xr[k] * W[k * DSTATE + col];
    part[p][s] = acc;
    __syncthreads();
    if (tid < 32) {
        float sum = 0.f;
#pragma unroll
        for (int pp = 0; pp < 8; ++pp) sum += part[pp][tid];
        if (tid < 16) Bm[(size_t)t * DSTATE + tid] = sum + bB[tid];
        else          Cm[(size_t)t * DSTATE + (tid - 16)] = sum + bC[tid - 16];
    }
}

// per-chunk state contribution S[bc][n][s] = sum_{t in chunk} w[t,n]*Bm[t,s]
__global__ __launch_bounds__(256)
void chunkS_k(const float* __restrict__ w, const float* __restrict__ Bm,
              float* __restrict__ S)
{
    int bc = blockIdx.x;              // b*NCHUNK + c
    int n0 = blockIdx.y * 16;
    int t0 = bc * CHUNK;
    __shared__ float wsh[CHUNK][16];
    __shared__ float bsh[CHUNK][17];
    int tid = threadIdx.x;
#pragma unroll
    for (int q = 0; q < 4; ++q) {
        int lin = tid + q * 256;
        int j = lin >> 4, col = lin & 15;
        wsh[j][col] = w[(size_t)(t0 + j) * DINNER + n0 + col];
        bsh[j][col] = Bm[(size_t)(t0 + j) * DSTATE + col];
    }
    __syncthreads();
    int ni = tid & 15, s = tid >> 4;
    float acc = 0.f;
#pragma unroll
    for (int j = 0; j < CHUNK; ++j)
        acc += wsh[j][ni] * bsh[j][s];
    S[((size_t)bc * DINNER + n0 + ni) * DSTATE + s] = acc;
}

// exclusive prefix over chunks: H[b][c][n][s] = sum_{c'<c} S[b][c'][n][s]
__global__ __launch_bounds__(256)
void hpre_k(const float* __restrict__ S, float* __restrict__ H)
{
    int idx = blockIdx.x * 256 + threadIdx.x;  // 0..32767
    int b  = idx >> 14;
    int ns = idx & 16383;
    float acc = 0.f;
    for (int c = 0; c < NCHUNK; ++c) {
        size_t off = ((size_t)(b * NCHUNK + c)) * (DINNER * DSTATE) + ns;
        H[off] = acc;
        acc += S[off];
    }
}

// y[l,n] = H[c(l)][n,:].Cm[l,:] + sum_{t<=l in chunk} (Cm[l].Bm[t]) * w[t,n]; g = y*silu(z)
// g aliases wbuf (each block stages its exclusive tile into LDS first).
__global__ __launch_bounds__(256)
void intra_k(const float* __restrict__ wbuf,
             const float* __restrict__ Bm, const float* __restrict__ Cm,
             const float* __restrict__ H,
             const float* __restrict__ xproj,
             float* __restrict__ g)
{
    int bc = blockIdx.x;              // b*NCHUNK + c
    int t0 = bc * CHUNK;
    int n0 = blockIdx.y * 64;
    __shared__ float wsh[CHUNK][65];
    __shared__ float Psh[CHUNK][CHUNK + 1];
    __shared__ float bsh[CHUNK][17];
    __shared__ float csh[CHUNK][17];
    int tid = threadIdx.x;
#pragma unroll
    for (int q = 0; q < 16; ++q) {
        int lin = tid + q * 256;
        int j = lin >> 6, col = lin & 63;
        wsh[j][col] = wbuf[(size_t)(t0 + j) * DINNER + n0 + col];
    }
#pragma unroll
    for (int q = 0; q < 4; ++q) {
        int lin = tid + q * 256;
        int j = lin >> 4, sc = lin & 15;
        bsh[j][sc] = Bm[(size_t)(t0 + j) * DSTATE + sc];
        csh[j][sc] = Cm[(size_t)(t0 + j) * DSTATE + sc];
    }
    __syncthreads();
#pragma unroll
    for (int q = 0; q < 16; ++q) {
        int lin = tid + q * 256;
        int l = lin >> 6, t = lin & 63;
        float p = 0.f;
#pragma unroll
        for (int s = 0; s < DSTATE; ++s) p += csh[l][s] * bsh[t][s];
        Psh[l][t] = p;
    }
    __syncthreads();
    int n  = tid & 63;
    int lg = tid >> 6;   // 0..3 (wave-uniform)
    float hv[DSTATE];
#pragma unroll
    for (int s = 0; s < DSTATE; ++s)
        hv[s] = H[(size_t)bc * (DINNER * DSTATE) + (size_t)(n0 + n) * DSTATE + s];
#pragma unroll
    for (int q = 0; q < 16; ++q) {
        int l = lg * 16 + q;
        float y = 0.f;
#pragma unroll
        for (int s = 0; s < DSTATE; ++s) y += hv[s] * csh[l][s];
        for (int t = 0; t <= l; ++t) y += Psh[l][t] * wsh[t][n];
        int token = t0 + l;
        float z = xproj[(size_t)token * (2 * DINNER) + DINNER + n0 + n];
        g[(size_t)token * DINNER + n0 + n] = y * silu_f(z);
    }
}

extern "C" void kernel_launch(void* const* d_in, const int* in_sizes, int n_in,
                              void* d_out, int out_size, void* d_ws, size_t ws_size,
                              hipStream_t stream) {
    const float* x      = (const float*)d_in[0];
    const float* w_in   = (const float*)d_in[1];
    const float* conv_k = (const float*)d_in[2];
    const float* conv_b = (const float*)d_in[3];
    const float* w_del  = (const float*)d_in[4];
    const float* b_del  = (const float*)d_in[5];
    const float* w_B    = (const float*)d_in[6];
    const float* b_B    = (const float*)d_in[7];
    const float* w_C    = (const float*)d_in[8];
    const float* b_C    = (const float*)d_in[9];
    const float* w_out  = (const float*)d_in[11];
    float* out = (float*)d_out;

    float* ws = (float*)d_ws;
    float* xproj = ws;                                   // 4096*2048
    float* xconv = xproj + (size_t)NTOK * 2 * DINNER;    // 4096*1024
    float* wbuf  = xconv + (size_t)NTOK * DINNER;        // 4096*1024 (later aliased as g)
    float* Bm    = wbuf  + (size_t)NTOK * DINNER;        // 4096*16
    float* Cm    = Bm    + (size_t)NTOK * DSTATE;
    float* S     = Cm    + (size_t)NTOK * DSTATE;        // 64*1024*16
    float* H     = S     + (size_t)2 * NCHUNK * DINNER * DSTATE;

    // 1. x_proj = x @ w_in
    gemm_k<0><<<dim3(2 * DINNER / BN, NTOK / BM), 256, 0, stream>>>(
        x, DMODEL, w_in, 2 * DINNER, xproj, 2 * DINNER,
        NTOK, 2 * DINNER, DMODEL, nullptr, nullptr);
    // 2. x_conv = silu(conv(x_z) + conv_b)
    gemm_k<1><<<dim3(DINNER / BN, NTOK / BM), 256, 0, stream>>>(
        xproj, 2 * DINNER, conv_k, DINNER, xconv, DINNER,
        NTOK, DINNER, 4 * DINNER, conv_b, nullptr);
    // 3. Bm, Cm
    bc_k<<<NTOK, 256, 0, stream>>>(xconv, w_B, b_B, w_C, b_C, Bm, Cm);
    // 4. w = softplus(xc@w_delta + b_delta) * xc * decay
    gemm_k<2><<<dim3(DINNER / BN, NTOK / BM), 256, 0, stream>>>(
        xconv, DINNER, w_del, DINNER, wbuf, DINNER,
        NTOK, DINNER, DINNER, b_del, xconv);
    // 5. per-chunk states
    chunkS_k<<<dim3(2 * NCHUNK, DINNER / 16), 256, 0, stream>>>(wbuf, Bm, S);
    // 6. exclusive prefix over chunks
    hpre_k<<<dim3(2 * DINNER * DSTATE / 256), 256, 0, stream>>>(S, H);
    // 7. intra-chunk + inter combine + gate; overwrites wbuf with g
    intra_k<<<dim3(2 * NCHUNK, DINNER / 64), 256, 0, stream>>>(
        wbuf, Bm, Cm, H, xproj, wbuf);
    // 8. out = g @ w_out
    gemm_k<0><<<dim3(DMODEL / BN, NTOK / BM), 256, 0, stream>>>(
        wbuf, DINNER, w_out, DMODEL, out, DMODEL,
        NTOK, DMODEL, DINNER, nullptr, nullptr);
}

// Round 2
// 299.823 us; speedup vs baseline: 3.5482x; 3.5482x over previous
//
#include <hip/hip_runtime.h>
#include <hip/hip_bf16.h>
#include <math.h>

#define DMODEL 512
#define DINNER 1024
#define DSTATE 16
#define SEQLEN 2048
#define NTOK   4096
#define CHUNK  64
#define NCHUNK (SEQLEN / CHUNK)  // 32

typedef __bf16 bf16x8 __attribute__((ext_vector_type(8)));
typedef float  f32x4  __attribute__((ext_vector_type(4)));

__device__ __forceinline__ float silu_f(float x) {
    return x / (1.0f + __expf(-x));
}

// ---------------------------------------------------------------------------
// bf16 MFMA GEMM: C[M][N] = A[M][K] @ W[K][N], W passed pre-transposed WT[N][K].
// 256 thr = 4 waves, tile 128x128, BK=32, wave owns 64x64 (4x4 frags of 16x16).
// MODE 0: xproj  — n<1024 -> Cb (bf16 x_z); n>=1024 -> C0 (f32 z, ldc 1024)
// MODE 1: conv   — A rows shifted by (k0>>10)-1 with batch-aware zero pad;
//                  epilogue silu(acc+bias[n]) -> C0 f32 + Cb bf16
// MODE 2: delta  — epilogue softplus(acc+bias[n]) * xc[m,n] * 0.95^(l+1) -> C0
// MODE 3: plain  — C0 = acc
// ---------------------------------------------------------------------------
template<int MODE>
__global__ __launch_bounds__(256)
void mgemm(const __hip_bfloat16* __restrict__ A, int lda,
           const __hip_bfloat16* __restrict__ WT, int ldw,
           float* __restrict__ C0, __hip_bfloat16* __restrict__ Cb, int ldc,
           int K,
           const float* __restrict__ bias, const float* __restrict__ xc)
{
    __shared__ __align__(16) __hip_bfloat16 As[128 * 40]; // +8 pad, 80B stride
    __shared__ __align__(16) __hip_bfloat16 Bs[128 * 40];

    const int tid = threadIdx.x;
    const int bm = blockIdx.y * 128;
    const int bn = blockIdx.x * 128;
    const int wid = tid >> 6, lane = tid & 63;
    const int wr = (wid >> 1) * 64, wc = (wid & 1) * 64;
    const int lhi = lane >> 4, llo = lane & 15;
    const int sr = tid >> 2;          // 0..63
    const int sk = (tid & 3) * 8;     // 0,8,16,24

    f32x4 acc[4][4] = {};

    for (int k0 = 0; k0 < K; k0 += 32) {
#pragma unroll
        for (int q = 0; q < 2; ++q) {
            int row = q * 64 + sr;
            int4 va;
            if (MODE == 1) {
                int kid = k0 >> 10;
                int i0  = k0 & 1023;
                int gr  = bm + row;
                int l2  = (gr & (SEQLEN - 1)) + kid - 1;
                if ((unsigned)l2 < (unsigned)SEQLEN)
                    va = *reinterpret_cast<const int4*>(A + (size_t)(gr + kid - 1) * lda + i0 + sk);
                else
                    va = make_int4(0, 0, 0, 0);
            } else {
                va = *reinterpret_cast<const int4*>(A + (size_t)(bm + row) * lda + k0 + sk);
            }
            *reinterpret_cast<int4*>(&As[row * 40 + sk]) = va;
            int4 vb = *reinterpret_cast<const int4*>(WT + (size_t)(bn + row) * ldw + k0 + sk);
            *reinterpret_cast<int4*>(&Bs[row * 40 + sk]) = vb;
        }
        __syncthreads();

        bf16x8 af[4], bfr[4];
#pragma unroll
        for (int i = 0; i < 4; ++i) {
            af[i]  = *reinterpret_cast<const bf16x8*>(&As[(wr + i * 16 + llo) * 40 + lhi * 8]);
            bfr[i] = *reinterpret_cast<const bf16x8*>(&Bs[(wc + i * 16 + llo) * 40 + lhi * 8]);
        }
#pragma unroll
        for (int i = 0; i < 4; ++i)
#pragma unroll
            for (int j = 0; j < 4; ++j)
                acc[i][j] = __builtin_amdgcn_mfma_f32_16x16x32_bf16(af[i], bfr[j], acc[i][j], 0, 0, 0);
        __syncthreads();
    }

#pragma unroll
    for (int i = 0; i < 4; ++i) {
#pragma unroll
        for (int q = 0; q < 4; ++q) {
            int m = bm + wr + i * 16 + lhi * 4 + q;
            float dec = 1.0f;
            if (MODE == 2)
                dec = __expf((float)((m & (SEQLEN - 1)) + 1) * -0.051293294f); // ln 0.95
#pragma unroll
            for (int j = 0; j < 4; ++j) {
                int n = bn + wc + j * 16 + llo;
                float v = acc[i][j][q];
                if (MODE == 0) {
                    if (n < DINNER)
                        Cb[(size_t)m * DINNER + n] = __float2bfloat16(v);
                    else
                        C0[(size_t)m * DINNER + (n - DINNER)] = v;
                } else if (MODE == 1) {
                    v = silu_f(v + bias[n]);
                    C0[(size_t)m * ldc + n] = v;
                    Cb[(size_t)m * ldc + n] = __float2bfloat16(v);
                } else if (MODE == 2) {
                    float d  = v + bias[n];
                    float sp = fmaxf(d, 0.f) + log1pf(__expf(-fabsf(d)));
                    C0[(size_t)m * ldc + n] = sp * xc[(size_t)m * DINNER + n] * dec;
                } else {
                    C0[(size_t)m * ldc + n] = v;
                }
            }
        }
    }
}

// 2D transpose + f32->bf16: out[C][R] from in[R][C]
__global__ __launch_bounds__(256)
void transpose_bf16_k(const float* __restrict__ in, __hip_bfloat16* __restrict__ out,
                      int R, int C)
{
    __shared__ float t[32][33];
    int bx = blockIdx.x * 32, by = blockIdx.y * 32;
    int tx = threadIdx.x & 31, ty = threadIdx.x >> 5;
#pragma unroll
    for (int q = 0; q < 4; ++q)
        t[ty + q * 8][tx] = in[(size_t)(by + ty + q * 8) * C + bx + tx];
    __syncthreads();
#pragma unroll
    for (int q = 0; q < 4; ++q)
        out[(size_t)(bx + ty + q * 8) * R + by + tx] = __float2bfloat16(t[tx][ty + q * 8]);
}

// f32 -> bf16 elementwise (n multiple of 1024)
__global__ __launch_bounds__(256)
void cvt_bf16_k(const float* __restrict__ in, __hip_bfloat16* __restrict__ out)
{
    int i = blockIdx.x * 256 + threadIdx.x;
    float4 v = reinterpret_cast<const float4*>(in)[i];
    __hip_bfloat16 tmp[4] = {__float2bfloat16(v.x), __float2bfloat16(v.y),
                             __float2bfloat16(v.z), __float2bfloat16(v.w)};
    *reinterpret_cast<ushort4*>(&out[(size_t)i * 4]) = *reinterpret_cast<const ushort4*>(tmp);
}

// Bm = xc@wB + bB ; Cm = xc@wC + bC   (one token per block)
__global__ __launch_bounds__(256)
void bc_k(const float* __restrict__ xc,
          const float* __restrict__ wB, const float* __restrict__ bB,
          const float* __restrict__ wC, const float* __restrict__ bC,
          float* __restrict__ Bm, float* __restrict__ Cm)
{
    __shared__ float xr[DINNER];
    __shared__ float part[8][32];
    int t = blockIdx.x;
    int tid = threadIdx.x;
#pragma unroll
    for (int q = 0; q < 4; ++q) {
        int i = tid + q * 256;
        xr[i] = xc[(size_t)t * DINNER + i];
    }
    __syncthreads();
    int s = tid & 31;
    int p = tid >> 5;
    const float* W = (s < 16) ? wB : wC;
    int col = s & 15;
    float acc = 0.f;
    for (int k = p * 128; k < p * 128 + 128; ++k)
        acc += xr[k] * W[k * DSTATE + col];
    part[p][s] = acc;
    __syncthreads();
    if (tid < 32) {
        float sum = 0.f;
#pragma unroll
        for (int pp = 0; pp < 8; ++pp) sum += part[pp][tid];
        if (tid < 16) Bm[(size_t)t * DSTATE + tid] = sum + bB[tid];
        else          Cm[(size_t)t * DSTATE + (tid - 16)] = sum + bC[tid - 16];
    }
}

// per-chunk state S[bc][n][s] = sum_{t in chunk} w[t,n]*Bm[t,s]
__global__ __launch_bounds__(256)
void chunkS_k(const float* __restrict__ w, const float* __restrict__ Bm,
              float* __restrict__ S)
{
    int bc = blockIdx.x;
    int n0 = blockIdx.y * 16;
    int t0 = bc * CHUNK;
    __shared__ float wsh[CHUNK][16];
    __shared__ float bsh[CHUNK][17];
    int tid = threadIdx.x;
#pragma unroll
    for (int q = 0; q < 4; ++q) {
        int lin = tid + q * 256;
        int j = lin >> 4, col = lin & 15;
        wsh[j][col] = w[(size_t)(t0 + j) * DINNER + n0 + col];
        bsh[j][col] = Bm[(size_t)(t0 + j) * DSTATE + col];
    }
    __syncthreads();
    int ni = tid & 15, s = tid >> 4;
    float acc = 0.f;
#pragma unroll
    for (int j = 0; j < CHUNK; ++j)
        acc += wsh[j][ni] * bsh[j][s];
    S[((size_t)bc * DINNER + n0 + ni) * DSTATE + s] = acc;
}

// exclusive prefix over chunks
__global__ __launch_bounds__(256)
void hpre_k(const float* __restrict__ S, float* __restrict__ H)
{
    int idx = blockIdx.x * 256 + threadIdx.x;
    int b  = idx >> 14;
    int ns = idx & 16383;
    float acc = 0.f;
    for (int c = 0; c < NCHUNK; ++c) {
        size_t off = ((size_t)(b * NCHUNK + c)) * (DINNER * DSTATE) + ns;
        H[off] = acc;
        acc += S[off];
    }
}

// intra-chunk + inter combine + gate -> gb (bf16)
__global__ __launch_bounds__(256)
void intra_k(const float* __restrict__ wbuf,
             const float* __restrict__ Bm, const float* __restrict__ Cm,
             const float* __restrict__ H,
             const float* __restrict__ zbuf,
             __hip_bfloat16* __restrict__ gb)
{
    int bc = blockIdx.x;
    int t0 = bc * CHUNK;
    int n0 = blockIdx.y * 64;
    __shared__ float wsh[CHUNK][65];
    __shared__ float Psh[CHUNK][CHUNK + 1];
    __shared__ float bsh[CHUNK][17];
    __shared__ float csh[CHUNK][17];
    int tid = threadIdx.x;
#pragma unroll
    for (int q = 0; q < 16; ++q) {
        int lin = tid + q * 256;
        int j = lin >> 6, col = lin & 63;
        wsh[j][col] = wbuf[(size_t)(t0 + j) * DINNER + n0 + col];
    }
#pragma unroll
    for (int q = 0; q < 4; ++q) {
        int lin = tid + q * 256;
        int j = lin >> 4, sc = lin & 15;
        bsh[j][sc] = Bm[(size_t)(t0 + j) * DSTATE + sc];
        csh[j][sc] = Cm[(size_t)(t0 + j) * DSTATE + sc];
    }
    __syncthreads();
#pragma unroll
    for (int q = 0; q < 16; ++q) {
        int lin = tid + q * 256;
        int l = lin >> 6, t = lin & 63;
        float p = 0.f;
#pragma unroll
        for (int s = 0; s < DSTATE; ++s) p += csh[l][s] * bsh[t][s];
        Psh[l][t] = p;
    }
    __syncthreads();
    int n  = tid & 63;
    int lg = tid >> 6;
    float hv[DSTATE];
#pragma unroll
    for (int s = 0; s < DSTATE; ++s)
        hv[s] = H[(size_t)bc * (DINNER * DSTATE) + (size_t)(n0 + n) * DSTATE + s];
#pragma unroll
    for (int q = 0; q < 16; ++q) {
        int l = lg * 16 + q;
        float y = 0.f;
#pragma unroll
        for (int s = 0; s < DSTATE; ++s) y += hv[s] * csh[l][s];
        for (int t = 0; t <= l; ++t) y += Psh[l][t] * wsh[t][n];
        int token = t0 + l;
        float z = zbuf[(size_t)token * DINNER + n0 + n];
        gb[(size_t)token * DINNER + n0 + n] = __float2bfloat16(y * silu_f(z));
    }
}

extern "C" void kernel_launch(void* const* d_in, const int* in_sizes, int n_in,
                              void* d_out, int out_size, void* d_ws, size_t ws_size,
                              hipStream_t stream) {
    const float* x      = (const float*)d_in[0];
    const float* w_in   = (const float*)d_in[1];
    const float* conv_k = (const float*)d_in[2];
    const float* conv_b = (const float*)d_in[3];
    const float* w_del  = (const float*)d_in[4];
    const float* b_del  = (const float*)d_in[5];
    const float* w_B    = (const float*)d_in[6];
    const float* b_B    = (const float*)d_in[7];
    const float* w_C    = (const float*)d_in[8];
    const float* b_C    = (const float*)d_in[9];
    const float* w_out  = (const float*)d_in[11];
    float* out = (float*)d_out;

    float* zbuf  = (float*)d_ws;                          // 4096*1024 f32
    float* xconv = zbuf  + (size_t)NTOK * DINNER;         // 4096*1024 f32
    float* wbuf  = xconv + (size_t)NTOK * DINNER;         // 4096*1024 f32
    float* Bm    = wbuf  + (size_t)NTOK * DINNER;
    float* Cm    = Bm    + (size_t)NTOK * DSTATE;
    float* S     = Cm    + (size_t)NTOK * DSTATE;         // 2*32*1024*16
    float* H     = S     + (size_t)2 * NCHUNK * DINNER * DSTATE;
    __hip_bfloat16* xb    = (__hip_bfloat16*)(H + (size_t)2 * NCHUNK * DINNER * DSTATE);
    __hip_bfloat16* xzb   = xb    + (size_t)NTOK * DMODEL;
    __hip_bfloat16* xcb   = xzb   + (size_t)NTOK * DINNER;
    __hip_bfloat16* gb    = xcb   + (size_t)NTOK * DINNER;
    __hip_bfloat16* winT  = gb    + (size_t)NTOK * DINNER;
    __hip_bfloat16* convT = winT  + (size_t)2 * DINNER * DMODEL;
    __hip_bfloat16* wdelT = convT + (size_t)4 * DINNER * DINNER;
    __hip_bfloat16* woutT = wdelT + (size_t)DINNER * DINNER;

    // weight prep
    cvt_bf16_k<<<NTOK * DMODEL / 1024, 256, 0, stream>>>(x, xb);
    transpose_bf16_k<<<dim3(2 * DINNER / 32, DMODEL / 32), 256, 0, stream>>>(w_in, winT, DMODEL, 2 * DINNER);
    transpose_bf16_k<<<dim3(DINNER / 32, 4 * DINNER / 32), 256, 0, stream>>>(conv_k, convT, 4 * DINNER, DINNER);
    transpose_bf16_k<<<dim3(DINNER / 32, DINNER / 32), 256, 0, stream>>>(w_del, wdelT, DINNER, DINNER);
    transpose_bf16_k<<<dim3(DMODEL / 32, DINNER / 32), 256, 0, stream>>>(w_out, woutT, DINNER, DMODEL);

    // 1. x_proj: x_z -> xzb (bf16), z -> zbuf (f32)
    mgemm<0><<<dim3(2 * DINNER / 128, NTOK / 128), 256, 0, stream>>>(
        xb, DMODEL, winT, DMODEL, zbuf, xzb, DINNER, DMODEL, nullptr, nullptr);
    // 2. conv: silu(conv(x_z)+b) -> xconv f32 + xcb bf16
    mgemm<1><<<dim3(DINNER / 128, NTOK / 128), 256, 0, stream>>>(
        xzb, DINNER, convT, 4 * DINNER, xconv, xcb, DINNER, 4 * DINNER, conv_b, nullptr);
    // 3. Bm, Cm
    bc_k<<<NTOK, 256, 0, stream>>>(xconv, w_B, b_B, w_C, b_C, Bm, Cm);
    // 4. w = softplus(xc@w_delta+b) * xc * decay -> wbuf f32
    mgemm<2><<<dim3(DINNER / 128, NTOK / 128), 256, 0, stream>>>(
        xcb, DINNER, wdelT, DINNER, wbuf, nullptr, DINNER, DINNER, b_del, xconv);
    // 5-7. scan
    chunkS_k<<<dim3(2 * NCHUNK, DINNER / 16), 256, 0, stream>>>(wbuf, Bm, S);
    hpre_k<<<dim3(2 * DINNER * DSTATE / 256), 256, 0, stream>>>(S, H);
    intra_k<<<dim3(2 * NCHUNK, DINNER / 64), 256, 0, stream>>>(wbuf, Bm, Cm, H, zbuf, gb);
    // 8. out = g @ w_out
    mgemm<3><<<dim3(DMODEL / 128, NTOK / 128), 256, 0, stream>>>(
        gb, DINNER, woutT, DINNER, out, nullptr, DMODEL, DINNER, nullptr, nullptr);
}